// Round 8
// baseline (400.280 us; speedup 1.0000x reference)
//
#include <hip/hip_runtime.h>
#include <math.h>

#define S_ 64
#define E_ 2048
#define H_ 32
#define D_ 64
#define L_ 2048
#define BS_ 16
#define BPS_ 128
#define QKV_N (3 * E_)   // 6144
#define CHUNK_CB 4       // cache blocks per chunk (= 64 tokens, 1 MB KV)
#define MAXCH 32         // max chunks per seq (128 cb / 4)
#define NIDS (S_ * MAXCH)

// ---------------------------------------------------------------------------
// Tall-skinny GEMM, stage 1 (UNCHANGED from R7): P[ky][64][N] = A @ B-chunk.
// ---------------------------------------------------------------------------
__global__ __launch_bounds__(256) void gemm_part(const float* __restrict__ A,
                                                 const float* __restrict__ B,
                                                 float* __restrict__ P,
                                                 int K, int N) {
    __shared__ float As[64][32];
    const int t    = threadIdx.x;
    const int lane = t & 63;
    const int mg   = t >> 6;
    const int colbase = blockIdx.x * 128 + lane * 2;
    const int kchunk  = K / gridDim.y;
    const int ks      = blockIdx.y * kchunk;

    float2 acc[16];
#pragma unroll
    for (int mm = 0; mm < 16; ++mm) acc[mm] = make_float2(0.f, 0.f);

    for (int k0 = ks; k0 < ks + kchunk; k0 += 32) {
        __syncthreads();
#pragma unroll
        for (int i = 0; i < 2; ++i) {
            int f4  = t + i * 256;
            int row = f4 >> 3, c4 = f4 & 7;
            *(float4*)&As[row][c4 * 4] =
                *(const float4*)(A + (size_t)row * K + k0 + c4 * 4);
        }
        __syncthreads();
#pragma unroll
        for (int kk = 0; kk < 32; kk += 4) {
            float2 b0 = *(const float2*)(B + (size_t)(k0 + kk + 0) * N + colbase);
            float2 b1 = *(const float2*)(B + (size_t)(k0 + kk + 1) * N + colbase);
            float2 b2 = *(const float2*)(B + (size_t)(k0 + kk + 2) * N + colbase);
            float2 b3 = *(const float2*)(B + (size_t)(k0 + kk + 3) * N + colbase);
#pragma unroll
            for (int mm = 0; mm < 16; ++mm) {
                float4 a = *(const float4*)&As[mg * 16 + mm][kk];
                acc[mm].x = fmaf(a.x, b0.x, acc[mm].x);
                acc[mm].y = fmaf(a.x, b0.y, acc[mm].y);
                acc[mm].x = fmaf(a.y, b1.x, acc[mm].x);
                acc[mm].y = fmaf(a.y, b1.y, acc[mm].y);
                acc[mm].x = fmaf(a.z, b2.x, acc[mm].x);
                acc[mm].y = fmaf(a.z, b2.y, acc[mm].y);
                acc[mm].x = fmaf(a.w, b3.x, acc[mm].x);
                acc[mm].y = fmaf(a.w, b3.y, acc[mm].y);
            }
        }
    }
    float* Pb = P + (size_t)blockIdx.y * 64 * N;
#pragma unroll
    for (int mm = 0; mm < 16; ++mm)
        *(float2*)(Pb + (size_t)(mg * 16 + mm) * N + colbase) = acc[mm];
}

__global__ __launch_bounds__(256) void reduce_add(const float* __restrict__ P,
                                                  const float* __restrict__ bias,
                                                  float* __restrict__ C,
                                                  int N, int nparts) {
    const int i4     = blockIdx.x * 256 + threadIdx.x;
    const int total4 = 64 * N / 4;
    const int col4   = i4 % (N / 4);
    float4 s = ((const float4*)bias)[col4];
    for (int k = 0; k < nparts; ++k) {
        float4 p = ((const float4*)P)[(size_t)k * total4 + i4];
        s.x += p.x; s.y += p.y; s.z += p.z; s.w += p.w;
    }
    ((float4*)C)[i4] = s;
}

// ---------------------------------------------------------------------------
// Paged attention, stage 1: persistent workers + dynamic chunk queue.
// Each block loops: grab id = atomicAdd(counter), decode s = id&63,
// c = id>>6 (chunk of 4 cache blocks = 64 tokens, all 32 heads, full-row
// streaming). Finished CUs immediately pull more work -> runtime load
// balance; tail = one 1 MB chunk. Empty ids (c beyond seq's ctx) are
// skipped in ~ns. Partials (m,l per head; acc[2048]) -> workspace.
// ---------------------------------------------------------------------------
__global__ __launch_bounds__(256, 4) void attn_row(
        const float* __restrict__ qkv,
        const float* __restrict__ kcache,
        const float* __restrict__ vcache,
        const int* __restrict__ btab,
        const int* __restrict__ clens,
        unsigned int* __restrict__ counter,
        float* __restrict__ ml,        // [S][MAXCH][H][2]
        float* __restrict__ pacc) {    // [S][MAXCH][2048]
    const int t = threadIdx.x;
    __shared__ int s_id;

    while (true) {
        __syncthreads();
        if (t == 0) s_id = (int)atomicAdd(counter, 1u);
        __syncthreads();
        const int id = s_id;
        if (id >= NIDS) return;

        const int s   = id & 63;
        const int c   = id >> 6;
        const int ctx = clens[s];
        const int nb  = (ctx + 15) >> 4;
        const int cb0 = c * CHUNK_CB;
        if (cb0 >= nb) continue;            // empty chunk id
        const int cb1 = min(cb0 + CHUNK_CB, nb);

        const float* qb = qkv + (size_t)s * QKV_N;
        const float4 q0 = *(const float4*)(qb + t * 4);
        const float4 q1 = *(const float4*)(qb + 1024 + t * 4);

        float m0 = -1e30f, l0 = 0.f, m1 = -1e30f, l1 = 0.f;
        float4 a0 = make_float4(0.f, 0.f, 0.f, 0.f);
        float4 a1 = make_float4(0.f, 0.f, 0.f, 0.f);

        const int* bt = btab + s * BPS_;
        for (int cb = cb0; cb < cb1; ++cb) {
            const int blk = bt[cb];
            const float* kb = kcache + (size_t)blk * (BS_ * H_ * D_);
            const float* vb = vcache + (size_t)blk * (BS_ * H_ * D_);
#pragma unroll 4
            for (int i = 0; i < 16; ++i) {
                const int   tok = cb * 16 + i;
                const int   off = i * 2048 + t * 4;
                const float4 k0 = *(const float4*)(kb + off);
                const float4 k1 = *(const float4*)(kb + off + 1024);
                const float4 v0 = *(const float4*)(vb + off);
                const float4 v1 = *(const float4*)(vb + off + 1024);

                float p0 = q0.x * k0.x + q0.y * k0.y + q0.z * k0.z + q0.w * k0.w;
                float p1 = q1.x * k1.x + q1.y * k1.y + q1.z * k1.z + q1.w * k1.w;
                p0 += __shfl_xor(p0, 1);  p1 += __shfl_xor(p1, 1);
                p0 += __shfl_xor(p0, 2);  p1 += __shfl_xor(p1, 2);
                p0 += __shfl_xor(p0, 4);  p1 += __shfl_xor(p1, 4);
                p0 += __shfl_xor(p0, 8);  p1 += __shfl_xor(p1, 8);

                const bool ok = tok < ctx;
                const float s0 = ok ? p0 * 0.125f : -1e38f;
                const float s1 = ok ? p1 * 0.125f : -1e38f;

                const float nm0 = fmaxf(m0, s0);
                const float r0  = __expf(m0 - nm0);
                const float e0  = __expf(s0 - nm0);
                m0 = nm0;
                l0 = fmaf(l0, r0, e0);
                a0.x = fmaf(e0, v0.x, a0.x * r0);
                a0.y = fmaf(e0, v0.y, a0.y * r0);
                a0.z = fmaf(e0, v0.z, a0.z * r0);
                a0.w = fmaf(e0, v0.w, a0.w * r0);

                const float nm1 = fmaxf(m1, s1);
                const float r1  = __expf(m1 - nm1);
                const float e1  = __expf(s1 - nm1);
                m1 = nm1;
                l1 = fmaf(l1, r1, e1);
                a1.x = fmaf(e1, v1.x, a1.x * r1);
                a1.y = fmaf(e1, v1.y, a1.y * r1);
                a1.z = fmaf(e1, v1.z, a1.z * r1);
                a1.w = fmaf(e1, v1.w, a1.w * r1);
            }
        }

        const int slot = s * MAXCH + c;
        *(float4*)&pacc[(size_t)slot * 2048 + t * 4]        = a0;
        *(float4*)&pacc[(size_t)slot * 2048 + 1024 + t * 4] = a1;
        if ((t & 15) == 0) {
            const int h0 = t >> 4;          // round-0 head
            ml[((size_t)slot * 32 + h0) * 2 + 0]        = m0;
            ml[((size_t)slot * 32 + h0) * 2 + 1]        = l0;
            ml[((size_t)slot * 32 + 16 + h0) * 2 + 0]   = m1;
            ml[((size_t)slot * 32 + 16 + h0) * 2 + 1]   = l1;
        }
    }
}

// ---------------------------------------------------------------------------
// Paged attention, stage 2: merge <=32 chunk partials + the new token.
// ---------------------------------------------------------------------------
__global__ __launch_bounds__(64) void attn_merge(
        const float* __restrict__ qkv,
        const int* __restrict__ clens,
        const float* __restrict__ ml,
        const float* __restrict__ pacc,
        float* __restrict__ attn) {
    const int sh = blockIdx.x;
    const int s  = sh >> 5;
    const int h  = sh & 31;
    const int d  = threadIdx.x;
    const int ctx = clens[s];
    const int nb  = (ctx + 15) >> 4;
    const int nch = (nb + CHUNK_CB - 1) / CHUNK_CB;

    float M = -1e30f, L = 0.f, O = 0.f;
    for (int c = 0; c < nch; ++c) {
        const int slot = s * MAXCH + c;
        const float mc = ml[((size_t)slot * 32 + h) * 2 + 0];
        const float lc = ml[((size_t)slot * 32 + h) * 2 + 1];
        const float oc = pacc[(size_t)slot * 2048 + h * 64 + d];
        const float nm = fmaxf(M, mc);
        const float ra = __expf(M - nm);
        const float rb = __expf(mc - nm);
        O = O * ra + oc * rb;
        L = L * ra + lc * rb;
        M = nm;
    }

    const float qd = qkv[(size_t)s * QKV_N + h * 64 + d];
    const float kd = qkv[(size_t)s * QKV_N + E_ + h * 64 + d];
    float part = qd * kd;
#pragma unroll
    for (int msk = 1; msk <= 32; msk <<= 1) part += __shfl_xor(part, msk);
    const float score = part * 0.125f;
    const float nm = fmaxf(M, score);
    const float r  = __expf(M - nm);
    const float p  = __expf(score - nm);
    const float vd = qkv[(size_t)s * QKV_N + 2 * E_ + h * 64 + d];
    O = O * r + p * vd;
    L = L * r + p;

    attn[(size_t)s * E_ + h * 64 + d] = O / L;
}

// ---------------------------------------------------------------------------
extern "C" void kernel_launch(void* const* d_in, const int* in_sizes, int n_in,
                              void* d_out, int out_size, void* d_ws, size_t ws_size,
                              hipStream_t stream) {
    const float* hidden = (const float*)d_in[0];
    const float* wqkv   = (const float*)d_in[1];
    const float* bqkv   = (const float*)d_in[2];
    const float* wout   = (const float*)d_in[3];
    const float* bout   = (const float*)d_in[4];
    const float* kcache = (const float*)d_in[5];
    const float* vcache = (const float*)d_in[6];
    const int*   btab   = (const int*)d_in[7];
    const int*   clens  = (const int*)d_in[8];
    float* out = (float*)d_out;

    float* qkv     = (float*)d_ws;                        // [64, 6144]
    float* attnbuf = qkv + (size_t)S_ * QKV_N;            // [64, 2048]
    float* part1   = attnbuf + (size_t)S_ * E_;           // [16][64][6144]
    float* part2   = part1 + (size_t)16 * S_ * QKV_N;     // [16][64][2048]
    // lifetime aliasing: part1/part2 are dead between reduce_add(1) and
    // gemm_part(3); attention partials + queue counter reuse that space.
    float* pacc    = part1;                               // [64][32][2048]
    float* ml      = part2;                               // [64][32][32][2]
    unsigned int* counter = (unsigned int*)(part2 + (size_t)S_ * MAXCH * 32 * 2);

    hipMemsetAsync(counter, 0, sizeof(unsigned int), stream);

    // 1) QKV projection: partials (KSPLIT=16 -> 768 blocks ~ 3/CU) + reduce
    gemm_part<<<dim3(QKV_N / 128, 16), 256, 0, stream>>>(hidden, wqkv, part1,
                                                         E_, QKV_N);
    reduce_add<<<dim3(S_ * QKV_N / 4 / 256), 256, 0, stream>>>(part1, bqkv,
                                                               qkv, QKV_N, 16);
    // 2a) persistent queue-balanced attention -> partials
    attn_row<<<dim3(1024), 256, 0, stream>>>(qkv, kcache, vcache, btab, clens,
                                             counter, ml, pacc);
    // 2b) merge partials + new token -> attnbuf [64, 2048]
    attn_merge<<<dim3(S_ * H_), 64, 0, stream>>>(qkv, clens, ml, pacc, attnbuf);
    // 3) output projection: partials (KSPLIT=16, 256 blocks) + reduce
    gemm_part<<<dim3(E_ / 128, 16), 256, 0, stream>>>(attnbuf, wout, part2,
                                                      E_, E_);
    reduce_add<<<dim3(S_ * E_ / 4 / 256), 256, 0, stream>>>(part2, bout,
                                                            out, E_, 16);
}

// Round 10
// 348.337 us; speedup vs baseline: 1.1491x; 1.1491x over previous
//
#include <hip/hip_runtime.h>
#include <math.h>

#define S_ 64
#define E_ 2048
#define H_ 32
#define D_ 64
#define L_ 2048
#define BS_ 16
#define BPS_ 128
#define QKV_N (3 * E_)   // 6144
#define KSPL 16          // k-split for both GEMMs
#define CHUNK_CB 8       // cache blocks per chunk (= 128 tokens)
#define MAXCH 16         // max chunks per seq

typedef float f32x4 __attribute__((ext_vector_type(4)));

__device__ __forceinline__ float4 ntload4(const float* p) {
    f32x4 v = __builtin_nontemporal_load((const f32x4*)p);
    return make_float4(v.x, v.y, v.z, v.w);
}
__device__ __forceinline__ void ntstore4(float* p, float4 v) {
    f32x4 u = {v.x, v.y, v.z, v.w};
    __builtin_nontemporal_store(u, (f32x4*)p);
}

// ---------------------------------------------------------------------------
// Tall-skinny GEMM, stage 1 (structure unchanged since R5):
// P[ky][64][N] = A[64, ks:ks+kc] @ B[ks:ks+kc, N].  Plain stores.
// ---------------------------------------------------------------------------
__global__ __launch_bounds__(256) void gemm_part(const float* __restrict__ A,
                                                 const float* __restrict__ B,
                                                 float* __restrict__ P,
                                                 int K, int N) {
    __shared__ float As[64][32];
    const int t    = threadIdx.x;
    const int lane = t & 63;
    const int mg   = t >> 6;
    const int colbase = blockIdx.x * 128 + lane * 2;
    const int kchunk  = K / gridDim.y;
    const int ks      = blockIdx.y * kchunk;

    float2 acc[16];
#pragma unroll
    for (int mm = 0; mm < 16; ++mm) acc[mm] = make_float2(0.f, 0.f);

    for (int k0 = ks; k0 < ks + kchunk; k0 += 32) {
        __syncthreads();
#pragma unroll
        for (int i = 0; i < 2; ++i) {
            int f4  = t + i * 256;
            int row = f4 >> 3, c4 = f4 & 7;
            *(float4*)&As[row][c4 * 4] =
                *(const float4*)(A + (size_t)row * K + k0 + c4 * 4);
        }
        __syncthreads();
#pragma unroll
        for (int kk = 0; kk < 32; kk += 4) {
            float2 b0 = *(const float2*)(B + (size_t)(k0 + kk + 0) * N + colbase);
            float2 b1 = *(const float2*)(B + (size_t)(k0 + kk + 1) * N + colbase);
            float2 b2 = *(const float2*)(B + (size_t)(k0 + kk + 2) * N + colbase);
            float2 b3 = *(const float2*)(B + (size_t)(k0 + kk + 3) * N + colbase);
#pragma unroll
            for (int mm = 0; mm < 16; ++mm) {
                float4 a = *(const float4*)&As[mg * 16 + mm][kk];
                acc[mm].x = fmaf(a.x, b0.x, acc[mm].x);
                acc[mm].y = fmaf(a.x, b0.y, acc[mm].y);
                acc[mm].x = fmaf(a.y, b1.x, acc[mm].x);
                acc[mm].y = fmaf(a.y, b1.y, acc[mm].y);
                acc[mm].x = fmaf(a.z, b2.x, acc[mm].x);
                acc[mm].y = fmaf(a.z, b2.y, acc[mm].y);
                acc[mm].x = fmaf(a.w, b3.x, acc[mm].x);
                acc[mm].y = fmaf(a.w, b3.y, acc[mm].y);
            }
        }
    }
    float* Pb = P + (size_t)blockIdx.y * 64 * N;
#pragma unroll
    for (int mm = 0; mm < 16; ++mm)
        *(float2*)(Pb + (size_t)(mg * 16 + mm) * N + colbase) = acc[mm];
}

// Final reduce for the OUTPUT projection only: C = bias + sum_k P[k].
__global__ __launch_bounds__(256) void reduce_add(const float* __restrict__ P,
                                                  const float* __restrict__ bias,
                                                  float* __restrict__ C,
                                                  int N, int nparts) {
    const int i4     = blockIdx.x * 256 + threadIdx.x;
    const int total4 = 64 * N / 4;
    const int col4   = i4 % (N / 4);
    float4 s = ((const float4*)bias)[col4];
    for (int k = 0; k < nparts; ++k) {
        float4 p = ((const float4*)P)[(size_t)k * total4 + i4];
        s.x += p.x; s.y += p.y; s.z += p.z; s.w += p.w;
    }
    ((float4*)C)[i4] = s;
}

// ---------------------------------------------------------------------------
// Paged attention, stage 1: full-row streaming chunks (R6 structure = best
// measured). One block = 8 cache blocks (128 tokens) of one seq, all heads.
// New vs R6: (a) q reduced inline from the 16 QKV-GEMM partials (+bias) --
// removes the reduce_add(1) launch; (b) K/V loads are NONTEMPORAL (stream-
// once data does not allocate in L2), pacc stores nontemporal too.
// ---------------------------------------------------------------------------
__global__ __launch_bounds__(256, 6) void attn_row(
        const float* __restrict__ part1,   // [KSPL][64][6144]
        const float* __restrict__ bqkv,
        const float* __restrict__ kcache,
        const float* __restrict__ vcache,
        const int* __restrict__ btab,
        const int* __restrict__ clens,
        float* __restrict__ ml,            // [S][MAXCH][H][2]
        float* __restrict__ pacc) {        // [S][MAXCH][2048]
    const int s   = blockIdx.x >> 4;
    const int c   = blockIdx.x & 15;
    const int ctx = clens[s];
    const int nb  = (ctx + 15) >> 4;
    const int cb0 = c * CHUNK_CB;
    if (cb0 >= nb) return;
    const int cb1 = min(cb0 + CHUNK_CB, nb);
    const int t   = threadIdx.x;

    // inline q reduction: q[s, t*4..] and q[s, 1024+t*4..] = bias + sum parts
    float4 q0 = *(const float4*)(bqkv + t * 4);
    float4 q1 = *(const float4*)(bqkv + 1024 + t * 4);
#pragma unroll 4
    for (int p = 0; p < KSPL; ++p) {
        const float* pp = part1 + (size_t)p * S_ * QKV_N + (size_t)s * QKV_N;
        float4 u0 = *(const float4*)(pp + t * 4);
        float4 u1 = *(const float4*)(pp + 1024 + t * 4);
        q0.x += u0.x; q0.y += u0.y; q0.z += u0.z; q0.w += u0.w;
        q1.x += u1.x; q1.y += u1.y; q1.z += u1.z; q1.w += u1.w;
    }

    float m0 = -1e30f, l0 = 0.f, m1 = -1e30f, l1 = 0.f;
    float4 a0 = make_float4(0.f, 0.f, 0.f, 0.f);
    float4 a1 = make_float4(0.f, 0.f, 0.f, 0.f);

    const int* bt = btab + s * BPS_;
    for (int cb = cb0; cb < cb1; ++cb) {
        const int blk = bt[cb];
        const float* kb = kcache + (size_t)blk * (BS_ * H_ * D_);
        const float* vb = vcache + (size_t)blk * (BS_ * H_ * D_);
#pragma unroll 2
        for (int i = 0; i < 16; ++i) {
            const int   tok = cb * 16 + i;
            const int   off = i * 2048 + t * 4;
            const float4 k0 = ntload4(kb + off);
            const float4 k1 = ntload4(kb + off + 1024);
            const float4 v0 = ntload4(vb + off);
            const float4 v1 = ntload4(vb + off + 1024);

            float p0 = q0.x * k0.x + q0.y * k0.y + q0.z * k0.z + q0.w * k0.w;
            float p1 = q1.x * k1.x + q1.y * k1.y + q1.z * k1.z + q1.w * k1.w;
            p0 += __shfl_xor(p0, 1);  p1 += __shfl_xor(p1, 1);
            p0 += __shfl_xor(p0, 2);  p1 += __shfl_xor(p1, 2);
            p0 += __shfl_xor(p0, 4);  p1 += __shfl_xor(p1, 4);
            p0 += __shfl_xor(p0, 8);  p1 += __shfl_xor(p1, 8);

            const bool ok = tok < ctx;
            const float s0 = ok ? p0 * 0.125f : -1e38f;
            const float s1 = ok ? p1 * 0.125f : -1e38f;

            const float nm0 = fmaxf(m0, s0);
            const float r0  = __expf(m0 - nm0);
            const float e0  = __expf(s0 - nm0);
            m0 = nm0;
            l0 = fmaf(l0, r0, e0);
            a0.x = fmaf(e0, v0.x, a0.x * r0);
            a0.y = fmaf(e0, v0.y, a0.y * r0);
            a0.z = fmaf(e0, v0.z, a0.z * r0);
            a0.w = fmaf(e0, v0.w, a0.w * r0);

            const float nm1 = fmaxf(m1, s1);
            const float r1  = __expf(m1 - nm1);
            const float e1  = __expf(s1 - nm1);
            m1 = nm1;
            l1 = fmaf(l1, r1, e1);
            a1.x = fmaf(e1, v1.x, a1.x * r1);
            a1.y = fmaf(e1, v1.y, a1.y * r1);
            a1.z = fmaf(e1, v1.z, a1.z * r1);
            a1.w = fmaf(e1, v1.w, a1.w * r1);
        }
    }

    const int slot = s * MAXCH + c;
    ntstore4(&pacc[(size_t)slot * 2048 + t * 4], a0);
    ntstore4(&pacc[(size_t)slot * 2048 + 1024 + t * 4], a1);
    if ((t & 15) == 0) {
        const int h0 = t >> 4;
        ml[((size_t)slot * 32 + h0) * 2 + 0]        = m0;
        ml[((size_t)slot * 32 + h0) * 2 + 1]        = l0;
        ml[((size_t)slot * 32 + 16 + h0) * 2 + 0]   = m1;
        ml[((size_t)slot * 32 + 16 + h0) * 2 + 1]   = l1;
    }
}

// ---------------------------------------------------------------------------
// Paged attention, stage 2: merge <=16 chunk partials + the new token.
// q/k_new/v_new for this (s,h) are reduced inline from the GEMM partials.
// ---------------------------------------------------------------------------
__global__ __launch_bounds__(64) void attn_merge(
        const float* __restrict__ part1,   // [KSPL][64][6144]
        const float* __restrict__ bqkv,
        const int* __restrict__ clens,
        const float* __restrict__ ml,
        const float* __restrict__ pacc,
        float* __restrict__ attn) {
    const int sh = blockIdx.x;
    const int s  = sh >> 5;
    const int h  = sh & 31;
    const int d  = threadIdx.x;
    const int ctx = clens[s];
    const int nb  = (ctx + 15) >> 4;
    const int nch = (nb + CHUNK_CB - 1) / CHUNK_CB;

    // inline reduction of q, k_new, v_new for column h*64+d
    const int col = h * 64 + d;
    float qd = bqkv[col], kd = bqkv[E_ + col], vd = bqkv[2 * E_ + col];
#pragma unroll 4
    for (int p = 0; p < KSPL; ++p) {
        const float* pp = part1 + (size_t)p * S_ * QKV_N + (size_t)s * QKV_N;
        qd += pp[col];
        kd += pp[E_ + col];
        vd += pp[2 * E_ + col];
    }

    float M = -1e30f, L = 0.f, O = 0.f;
    for (int c = 0; c < nch; ++c) {
        const int slot = s * MAXCH + c;
        const float mc = ml[((size_t)slot * 32 + h) * 2 + 0];
        const float lc = ml[((size_t)slot * 32 + h) * 2 + 1];
        const float oc = pacc[(size_t)slot * 2048 + h * 64 + d];
        const float nm = fmaxf(M, mc);
        const float ra = __expf(M - nm);
        const float rb = __expf(mc - nm);
        O = O * ra + oc * rb;
        L = L * ra + lc * rb;
        M = nm;
    }

    float part = qd * kd;
#pragma unroll
    for (int msk = 1; msk <= 32; msk <<= 1) part += __shfl_xor(part, msk);
    const float score = part * 0.125f;
    const float nm = fmaxf(M, score);
    const float r  = __expf(M - nm);
    const float p  = __expf(score - nm);
    O = O * r + p * vd;
    L = L * r + p;

    attn[(size_t)s * E_ + h * 64 + d] = O / L;
}

// ---------------------------------------------------------------------------
extern "C" void kernel_launch(void* const* d_in, const int* in_sizes, int n_in,
                              void* d_out, int out_size, void* d_ws, size_t ws_size,
                              hipStream_t stream) {
    const float* hidden = (const float*)d_in[0];
    const float* wqkv   = (const float*)d_in[1];
    const float* bqkv   = (const float*)d_in[2];
    const float* wout   = (const float*)d_in[3];
    const float* bout   = (const float*)d_in[4];
    const float* kcache = (const float*)d_in[5];
    const float* vcache = (const float*)d_in[6];
    const int*   btab   = (const int*)d_in[7];
    const int*   clens  = (const int*)d_in[8];
    float* out = (float*)d_out;

    // workspace layout (34.4 MB total; <= proven 35.6 MB footprint)
    float* part1   = (float*)d_ws;                        // [16][64][6144] 25.2MB
    float* attnbuf = part1 + (size_t)KSPL * S_ * QKV_N;   // [64][2048]  0.52MB
    float* pacc    = attnbuf + (size_t)S_ * E_;           // [64][16][2048] 8.4MB
    float* ml      = pacc + (size_t)S_ * MAXCH * 2048;    // [64][16][32][2] 0.26MB
    // part2 aliases pacc: pacc is dead after attn_merge, exactly same size.
    float* part2   = pacc;                                // [16][64][2048]

    // 1) QKV projection partials (no reduce launch -- consumers reduce inline)
    gemm_part<<<dim3(QKV_N / 128, KSPL), 256, 0, stream>>>(hidden, wqkv, part1,
                                                           E_, QKV_N);
    // 2a) full-row chunked attention -> partials (nontemporal KV streaming)
    attn_row<<<dim3(S_ * MAXCH), 256, 0, stream>>>(part1, bqkv, kcache, vcache,
                                                   btab, clens, ml, pacc);
    // 2b) merge chunk partials + new token -> attnbuf [64, 2048]
    attn_merge<<<dim3(S_ * H_), 64, 0, stream>>>(part1, bqkv, clens, ml, pacc,
                                                 attnbuf);
    // 3) output projection: partials then reduce+bias -> d_out
    gemm_part<<<dim3(E_ / 128, KSPL), 256, 0, stream>>>(attnbuf, wout, part2,
                                                        E_, E_);
    reduce_add<<<dim3(S_ * E_ / 4 / 256), 256, 0, stream>>>(part2, bout,
                                                            out, E_, KSPL);
}